// Round 1
// baseline (392.066 us; speedup 1.0000x reference)
//
#include <hip/hip_runtime.h>

#define N_NODES 100000
#define N_EDGES 1600000
#define IN_F    128
#define NEG_SLOPE 0.2f
#define NBUCK   512                 // bucket = dst>>8; 391 active
#define BCAP    5120                // padded bucket capacity (mean 4096, +16 sigma)
#define PCHUNK  4096                // edges per partition block
#define PGRID   391                 // ceil(N_EDGES / PCHUNK)
#define GEMMGRID 1563               // ceil(N_NODES / 64)

typedef __attribute__((ext_vector_type(8))) short bf16x8;
typedef __attribute__((ext_vector_type(4))) float f32x4;

__device__ __forceinline__ float bf2f(unsigned short u) {
    return __uint_as_float(((unsigned int)u) << 16);
}

// f32 -> bf16 round-to-nearest-even
__device__ __forceinline__ unsigned short f2bf(float f) {
    unsigned int u = __float_as_uint(f);
    u += 0x7FFFu + ((u >> 16) & 1u);
    return (unsigned short)(u >> 16);
}

// ---------------------------------------------------------------------------
// K1: cursor init (blocks 0..1) + weight pack (blocks 2..161).
// Pack layout: Wp[((nt*4+kt)*64+lane)*8+j] = W[kt*32+(lane>>4)*8+j][nt*16+(lane&15)]
// ---------------------------------------------------------------------------
__global__ __launch_bounds__(256) void init_pack(int* __restrict__ bcursor,
                                                 const float* __restrict__ W0,
                                                 const float* __restrict__ W1,
                                                 const float* __restrict__ W2,
                                                 const float* __restrict__ rW2,
                                                 unsigned short* __restrict__ W0p,
                                                 unsigned short* __restrict__ W1p,
                                                 unsigned short* __restrict__ W2p) {
    const int t = threadIdx.x;
    if (blockIdx.x < 2) {
        int i = blockIdx.x * 256 + t;
        if (i < NBUCK) bcursor[i] = i * BCAP;
        return;
    }
    int gid = (blockIdx.x - 2) * 256 + t;            // < 40960
    const float* W;
    unsigned short* Wp;
    int idx, ncols;
    if (gid < 16384)      { W = W0; Wp = W0p; idx = gid;          ncols = 128; }
    else if (gid < 32768) { W = W1; Wp = W1p; idx = gid - 16384;  ncols = 128; }
    else                  { W = W2; Wp = W2p; idx = gid - 32768;  ncols = 32;  }
    int j  = idx & 7;
    int l  = (idx >> 3) & 63;
    int kt = (idx >> 9) & 3;
    int nt = idx >> 11;
    int k  = kt * 32 + (l >> 4) * 8 + j;
    int n  = nt * 16 + (l & 15);
    float v;
    if (ncols == 128) v = W[k * 128 + n];
    else              v = (n < 16) ? W[k * 16 + n] : rW2[k * 16 + (n - 16)];
    Wp[idx] = f2bf(v);
}

// ---------------------------------------------------------------------------
// K2: edge partition into padded buckets (blocks [0,PGRID)) + layer-0 MFMA
// GEMM (blocks [PGRID, PGRID+GEMMGRID)).
// ---------------------------------------------------------------------------
__global__ __launch_bounds__(256) void part_gemm0(const int* __restrict__ src,
                                                  const int* __restrict__ dst,
                                                  int* __restrict__ bcursor,
                                                  unsigned int* __restrict__ pe, int nE,
                                                  const float* __restrict__ A,
                                                  const unsigned short* __restrict__ Wp,
                                                  const float* __restrict__ al,
                                                  const float* __restrict__ ar,
                                                  unsigned short* __restrict__ featb,
                                                  float* __restrict__ el,
                                                  float* __restrict__ er,
                                                  int nrows) {
    __shared__ int hist[NBUCK];
    __shared__ int lstart[NBUCK];
    __shared__ int gbase[NBUCK];
    __shared__ int curB[NBUCK];
    __shared__ int s[NBUCK];
    __shared__ unsigned int reorder[PCHUNK];

    const int t = threadIdx.x;

    if (blockIdx.x < PGRID) {
        const int start = blockIdx.x * PCHUNK;

        hist[t] = 0; hist[t + 256] = 0;
        __syncthreads();
#pragma unroll
        for (int j = 0; j < PCHUNK / 256; ++j) {
            int e = start + j * 256 + t;
            if (e < nE) atomicAdd(&hist[dst[e] >> 8], 1);
        }
        __syncthreads();
        const int c0 = hist[t];
        const int c1 = hist[t + 256];
        s[t] = c0; s[t + 256] = c1;
        __syncthreads();
        // 512-wide inclusive scan with 256 threads
#pragma unroll
        for (int off = 1; off <= 256; off <<= 1) {
            int x0 = (t >= off) ? s[t - off] : 0;
            int x1 = s[t + 256 - off];
            __syncthreads();
            s[t] += x0; s[t + 256] += x1;
            __syncthreads();
        }
        lstart[t]       = s[t] - c0;
        lstart[t + 256] = s[t + 256] - c1;
        curB[t]         = s[t] - c0;
        curB[t + 256]   = s[t + 256] - c1;
        gbase[t]        = c0 ? atomicAdd(&bcursor[t],       c0) : 0;
        gbase[t + 256]  = c1 ? atomicAdd(&bcursor[t + 256], c1) : 0;
        __syncthreads();

#pragma unroll
        for (int j = 0; j < PCHUNK / 256; ++j) {
            int e = start + j * 256 + t;
            if (e < nE) {
                int d  = dst[e];
                int sv = src[e];
                int b  = d >> 8;
                int pos = atomicAdd(&curB[b], 1);
                reorder[pos] = ((unsigned)sv << 8) | ((unsigned)d & 255u);
            }
        }
        __syncthreads();

        // flush: one thread per bucket writes its contiguous run
        for (int b = t; b < NBUCK; b += 256) {
            int st = lstart[b];
            int en = curB[b];
            int gb = gbase[b];
            for (int k = st; k < en; ++k)
                pe[gb + (k - st)] = reorder[k];
        }
    } else {
        // ---------------- layer-0 GEMM ----------------
        const int bid  = blockIdx.x - PGRID;
        const int wv   = t >> 6;
        const int lane = t & 63;
        const int q    = lane >> 4;
        const int m    = lane & 15;
        const int rb   = bid * 64 + wv * 16;
        const int arow = rb + m;
        const bool rok = arow < nrows;
        const float* Ar = A + (size_t)arow * IN_F;

        f32x4 acc[8];
#pragma unroll
        for (int nt = 0; nt < 8; ++nt) acc[nt] = (f32x4){0.f, 0.f, 0.f, 0.f};

#pragma unroll
        for (int kt = 0; kt < 4; ++kt) {
            bf16x8 afr = (bf16x8){0, 0, 0, 0, 0, 0, 0, 0};
            if (rok) {
                float4 v0 = *(const float4*)(Ar + kt * 32 + q * 8);
                float4 v1 = *(const float4*)(Ar + kt * 32 + q * 8 + 4);
                afr[0] = (short)f2bf(v0.x); afr[1] = (short)f2bf(v0.y);
                afr[2] = (short)f2bf(v0.z); afr[3] = (short)f2bf(v0.w);
                afr[4] = (short)f2bf(v1.x); afr[5] = (short)f2bf(v1.y);
                afr[6] = (short)f2bf(v1.z); afr[7] = (short)f2bf(v1.w);
            }
#pragma unroll
            for (int nt = 0; nt < 8; ++nt) {
                bf16x8 bfr = *(const bf16x8*)(Wp + ((size_t)(nt * 4 + kt) * 64 + lane) * 8);
                acc[nt] = __builtin_amdgcn_mfma_f32_16x16x32_bf16(afr, bfr, acc[nt], 0, 0, 0);
            }
        }

        float pel[16], per[16];
#pragma unroll
        for (int i = 0; i < 16; ++i) { pel[i] = 0.f; per[i] = 0.f; }

#pragma unroll
        for (int nt = 0; nt < 8; ++nt) {
            const int col = nt * 16 + m;
            const float alv = al[col];
            const float arv = ar[col];
            const int h = nt >> 1;
#pragma unroll
            for (int reg = 0; reg < 4; ++reg) {
                int row = rb + q * 4 + reg;
                float a = acc[nt][reg];
                if (row < nrows) featb[(size_t)row * 128 + col] = f2bf(a);
                pel[reg * 4 + h] += a * alv;
                per[reg * 4 + h] += a * arv;
            }
        }
#pragma unroll
        for (int sh = 8; sh > 0; sh >>= 1) {
#pragma unroll
            for (int i = 0; i < 16; ++i) {
                pel[i] += __shfl_down(pel[i], sh);
                per[i] += __shfl_down(per[i], sh);
            }
        }
        if (m == 0) {
#pragma unroll
            for (int reg = 0; reg < 4; ++reg) {
                int row = rb + q * 4 + reg;
                if (row < nrows) {
#pragma unroll
                    for (int h = 0; h < 4; ++h) {
                        el[row * 4 + h] = pel[reg * 4 + h];
                        er[row * 4 + h] = per[reg * 4 + h];
                    }
                }
            }
        }
    }
}

// ---------------------------------------------------------------------------
// K3: per-bucket finalize — degree histogram + local scan -> rowptr/deg,
// within-bucket sort -> sorted_src (padded space, base = b*BCAP).
// ---------------------------------------------------------------------------
__global__ __launch_bounds__(256) void bucket_finalize(const unsigned int* __restrict__ pe,
                                                       const int* __restrict__ bcursor,
                                                       int* __restrict__ rowptr,
                                                       int* __restrict__ deg,
                                                       int* __restrict__ sorted_src) {
    __shared__ int deg_l[256];
    __shared__ int s[256];
    __shared__ int cur[256];

    const int b  = blockIdx.x;
    const int t  = threadIdx.x;
    const int base = b * BCAP;
    const int cnt  = bcursor[b] - base;
    const int n    = b * 256 + t;

    deg_l[t] = 0;
    __syncthreads();
    for (int i = t; i < cnt; i += 256)
        atomicAdd(&deg_l[pe[base + i] & 255u], 1);
    __syncthreads();

    const int dv = deg_l[t];
    s[t] = dv;
    __syncthreads();
#pragma unroll
    for (int off = 1; off < 256; off <<= 1) {
        int x = (t >= off) ? s[t - off] : 0;
        __syncthreads();
        s[t] += x;
        __syncthreads();
    }
    const int off_l = s[t] - dv;
    if (n < N_NODES) {
        rowptr[n] = base + off_l;
        deg[n]    = dv;
    }
    cur[t] = off_l;
    __syncthreads();

    for (int i = t; i < cnt; i += 256) {
        unsigned int ed = pe[base + i];
        int pos = atomicAdd(&cur[ed & 255u], 1);
        sorted_src[base + pos] = (int)(ed >> 8);
    }
}

// ---------------------------------------------------------------------------
// MFMA GEMM, bf16 A (layer 1): featb = Ab @ Wp, el/er fused. Barrier-free.
// ---------------------------------------------------------------------------
__global__ __launch_bounds__(256) void gemm128_mfma_bf16(const unsigned short* __restrict__ Ab,
                                                         const unsigned short* __restrict__ Wp,
                                                         const float* __restrict__ al,
                                                         const float* __restrict__ ar,
                                                         unsigned short* __restrict__ featb,
                                                         float* __restrict__ el,
                                                         float* __restrict__ er,
                                                         int nrows) {
    const int t    = threadIdx.x;
    const int wv   = t >> 6;
    const int lane = t & 63;
    const int q    = lane >> 4;
    const int m    = lane & 15;
    const int rb   = blockIdx.x * 64 + wv * 16;
    const int arow = rb + m;
    const bool rok = arow < nrows;
    const unsigned short* Ar = Ab + (size_t)arow * IN_F;

    f32x4 acc[8];
#pragma unroll
    for (int nt = 0; nt < 8; ++nt) acc[nt] = (f32x4){0.f, 0.f, 0.f, 0.f};

#pragma unroll
    for (int kt = 0; kt < 4; ++kt) {
        bf16x8 afr = (bf16x8){0, 0, 0, 0, 0, 0, 0, 0};
        if (rok) afr = *(const bf16x8*)(Ar + kt * 32 + q * 8);
#pragma unroll
        for (int nt = 0; nt < 8; ++nt) {
            bf16x8 bfr = *(const bf16x8*)(Wp + ((size_t)(nt * 4 + kt) * 64 + lane) * 8);
            acc[nt] = __builtin_amdgcn_mfma_f32_16x16x32_bf16(afr, bfr, acc[nt], 0, 0, 0);
        }
    }

    float pel[16], per[16];
#pragma unroll
    for (int i = 0; i < 16; ++i) { pel[i] = 0.f; per[i] = 0.f; }

#pragma unroll
    for (int nt = 0; nt < 8; ++nt) {
        const int col = nt * 16 + m;
        const float alv = al[col];
        const float arv = ar[col];
        const int h = nt >> 1;
#pragma unroll
        for (int reg = 0; reg < 4; ++reg) {
            int row = rb + q * 4 + reg;
            float a = acc[nt][reg];
            if (row < nrows) featb[(size_t)row * 128 + col] = f2bf(a);
            pel[reg * 4 + h] += a * alv;
            per[reg * 4 + h] += a * arv;
        }
    }
#pragma unroll
    for (int sh = 8; sh > 0; sh >>= 1) {
#pragma unroll
        for (int i = 0; i < 16; ++i) {
            pel[i] += __shfl_down(pel[i], sh);
            per[i] += __shfl_down(per[i], sh);
        }
    }
    if (m == 0) {
#pragma unroll
        for (int reg = 0; reg < 4; ++reg) {
            int row = rb + q * 4 + reg;
            if (row < nrows) {
#pragma unroll
                for (int h = 0; h < 4; ++h) {
                    el[row * 4 + h] = pel[reg * 4 + h];
                    er[row * 4 + h] = per[reg * 4 + h];
                }
            }
        }
    }
}

// ---------------------------------------------------------------------------
// MFMA dual GEMM layer 2 (bf16 A): [feat2b(bf16) | res2(f32)] = A @ [W2|resW2].
// ---------------------------------------------------------------------------
__global__ __launch_bounds__(256) void gemm16_mfma(const unsigned short* __restrict__ Ab,
                                                   const unsigned short* __restrict__ Wp,
                                                   const float* __restrict__ al,
                                                   const float* __restrict__ ar,
                                                   unsigned short* __restrict__ feat2b,
                                                   float* __restrict__ res2,
                                                   float* __restrict__ el,
                                                   float* __restrict__ er,
                                                   int nrows) {
    const int t    = threadIdx.x;
    const int wv   = t >> 6;
    const int lane = t & 63;
    const int q    = lane >> 4;
    const int m    = lane & 15;
    const int rb   = blockIdx.x * 64 + wv * 16;
    const int arow = rb + m;
    const bool rok = arow < nrows;
    const unsigned short* Ar = Ab + (size_t)arow * IN_F;

    f32x4 acc0 = (f32x4){0.f, 0.f, 0.f, 0.f};
    f32x4 acc1 = (f32x4){0.f, 0.f, 0.f, 0.f};

#pragma unroll
    for (int kt = 0; kt < 4; ++kt) {
        bf16x8 afr = (bf16x8){0, 0, 0, 0, 0, 0, 0, 0};
        if (rok) afr = *(const bf16x8*)(Ar + kt * 32 + q * 8);
        bf16x8 b0 = *(const bf16x8*)(Wp + ((size_t)(0 * 4 + kt) * 64 + lane) * 8);
        bf16x8 b1 = *(const bf16x8*)(Wp + ((size_t)(1 * 4 + kt) * 64 + lane) * 8);
        acc0 = __builtin_amdgcn_mfma_f32_16x16x32_bf16(afr, b0, acc0, 0, 0, 0);
        acc1 = __builtin_amdgcn_mfma_f32_16x16x32_bf16(afr, b1, acc1, 0, 0, 0);
    }

    float pel[4], per[4];
    const float alv = al[m];
    const float arv = ar[m];
#pragma unroll
    for (int reg = 0; reg < 4; ++reg) {
        int row = rb + q * 4 + reg;
        float a = acc0[reg];
        if (row < nrows) {
            feat2b[(size_t)row * 16 + m] = f2bf(a);
            res2[(size_t)row * 16 + m]   = acc1[reg];
        }
        pel[reg] = a * alv;
        per[reg] = a * arv;
    }
#pragma unroll
    for (int sh = 8; sh > 0; sh >>= 1) {
#pragma unroll
        for (int reg = 0; reg < 4; ++reg) {
            pel[reg] += __shfl_down(pel[reg], sh);
            per[reg] += __shfl_down(per[reg], sh);
        }
    }
    if (m == 0) {
#pragma unroll
        for (int reg = 0; reg < 4; ++reg) {
            int row = rb + q * 4 + reg;
            if (row < nrows) { el[row] = pel[reg]; er[row] = per[reg]; }
        }
    }
}

// ---------------------------------------------------------------------------
// Pull aggregation, H=4, D=32, bf16 gathers, wave per node, bf16 in/out.
//
// v2: 16-deep double-banked gather pipeline.
//  - Row index is wave-uniform per edge -> v_readlane puts the row base in
//    SGPRs; per-lane offset (lane*4B) is loop-invariant -> global_load saddr
//    form, ~zero VALU address math per gather (was ~5 VALU of 64-bit math).
//  - Chunk of 16 gathers issued back-to-back; next chunk's 16 issued BEFORE
//    consuming the current one (banks u/v), so a gather round-trip is exposed
//    once per 16 edges instead of once per 4.
//  - Chunk 0 issues before the el-gather/exp weight phase, hiding that
//    latency under the feature gathers. sS LDS dropped entirely.
//  - Load *pattern* unchanged: full-row 256B, ushort2 per lane (the two prior
//    regressions came from changing the access pattern, not scheduling).
// ---------------------------------------------------------------------------
#define LOAD16(B, START, CNT)                                                  \
    {                                                                          \
        _Pragma("unroll")                                                      \
        for (int jg_ = 0; jg_ < 16; jg_ += 4) {                                \
            if (jg_ < (CNT)) {                                                 \
                _Pragma("unroll")                                              \
                for (int k_ = 0; k_ < 4; ++k_) {                               \
                    int sj_ = __builtin_amdgcn_readlane(s_own, (START) + jg_ + k_); \
                    const unsigned short* rp_ = featb + (size_t)sj_ * 128;     \
                    (B)[jg_ + k_] = *((const ushort2*)rp_ + lane);             \
                }                                                              \
            }                                                                  \
        }                                                                      \
    }

__global__ __launch_bounds__(256) void gat_agg128(const int* __restrict__ rowptr,
                                                  const int* __restrict__ deg,
                                                  const int* __restrict__ sorted_src,
                                                  const float* __restrict__ el,
                                                  const float* __restrict__ er,
                                                  const unsigned short* __restrict__ featb,
                                                  const unsigned short* __restrict__ resb,
                                                  unsigned short* __restrict__ outb) {
    __shared__ float sW[4][64][4];

    const int wv   = threadIdx.x >> 6;
    const int lane = threadIdx.x & 63;
    const int nd   = blockIdx.x * 4 + wv;

    const int dg = deg[nd];
    const int r0 = rowptr[nd];
    const int h  = lane >> 4;
    const float4 er4 = *(const float4*)(er + nd * 4);

    float den = 0.f;
    float ax = 0.f, ay = 0.f;

    for (int base = 0; base < dg; base += 64) {
        int m = dg - base; if (m > 64) m = 64;

        // stage: every lane owns one edge (sentinel src=0, weight=0 beyond m)
        int s_own = 0;
        if (lane < m) s_own = sorted_src[r0 + base + lane];

        // issue chunk 0 gathers BEFORE the weight phase (overlap exp latency)
        ushort2 u[16], v[16];
        int c = m < 16 ? m : 16;
        LOAD16(u, 0, c)

        float4 w4;
        if (lane < m) {
            float4 e4 = *(const float4*)(el + s_own * 4);
            float t_;
            t_ = e4.x + er4.x; t_ = t_ > 0.f ? t_ : NEG_SLOPE * t_; w4.x = __expf(t_);
            t_ = e4.y + er4.y; t_ = t_ > 0.f ? t_ : NEG_SLOPE * t_; w4.y = __expf(t_);
            t_ = e4.z + er4.z; t_ = t_ > 0.f ? t_ : NEG_SLOPE * t_; w4.z = __expf(t_);
            t_ = e4.w + er4.w; t_ = t_ > 0.f ? t_ : NEG_SLOPE * t_; w4.w = __expf(t_);
        } else {
            w4.x = 0.f; w4.y = 0.f; w4.z = 0.f; w4.w = 0.f;
        }
        // wave-synchronous: same wave writes and reads its sW slice
        *(float4*)(&sW[wv][lane][0]) = w4;

        int i = 0;
        while (true) {
            int in_ = i + c;
            int cn = m - in_; if (cn > 16) cn = 16;
            if (cn > 0) LOAD16(v, in_, cn)

            // consume bank u: weight read is ds_read with literal offset
            const float* wb = &sW[wv][i][h];
#pragma unroll
            for (int jg = 0; jg < 16; jg += 4) {
                if (jg < c) {
#pragma unroll
                    for (int k = 0; k < 4; ++k) {
                        float w = wb[(jg + k) * 4];   // 0 for padded edges
                        ushort2 uu = u[jg + k];
                        den += w;
                        ax += w * bf2f(uu.x);
                        ay += w * bf2f(uu.y);
                    }
                }
            }
            if (cn <= 0) break;
#pragma unroll
            for (int k = 0; k < 16; ++k) u[k] = v[k];
            i = in_; c = cn;
        }
    }

    float scale = den > 0.f ? 1.f / den : 0.f;
    float ox = ax * scale, oy = ay * scale;
    size_t o0 = (size_t)nd * 128 + lane * 2;
    if (resb) {
        ushort2 rv = *(const ushort2*)(resb + o0);
        ox += bf2f(rv.x);
        oy += bf2f(rv.y);
    }
    ox = fmaxf(ox, 0.f);
    oy = fmaxf(oy, 0.f);
    ushort2 ou;
    ou.x = f2bf(ox);
    ou.y = f2bf(oy);
    *(ushort2*)(outb + o0) = ou;
}

// ---------------------------------------------------------------------------
// Pull aggregation, H=1, C=16: wave per node, LDS staging, 8 edge-groups of
// 8 lanes; lane owns a feature pair. Final output f32 (+res2).
// ---------------------------------------------------------------------------
__global__ __launch_bounds__(256) void gat_agg16(const int* __restrict__ rowptr,
                                                 const int* __restrict__ deg,
                                                 const int* __restrict__ sorted_src,
                                                 const float* __restrict__ el,
                                                 const float* __restrict__ er,
                                                 const unsigned short* __restrict__ feat2b,
                                                 const float* __restrict__ res,
                                                 float* __restrict__ out) {
    __shared__ int   sS[4][64];
    __shared__ float sW[4][64];

    const int wv   = threadIdx.x >> 6;
    const int lane = threadIdx.x & 63;
    const int nd   = blockIdx.x * 4 + (threadIdx.x >> 6);
    const int g    = lane >> 3;
    const int f2   = (lane & 7) * 2;

    const int dg = deg[nd];
    const int r0 = rowptr[nd];
    const float erd = er[nd];

    float ax = 0.f, ay = 0.f, den = 0.f;

    for (int base = 0; base < dg; base += 64) {
        int m = dg - base; if (m > 64) m = 64;
        if (lane < m) {
            int s = sorted_src[r0 + base + lane];
            sS[wv][lane] = s;
            float v = el[s] + erd;
            v = v > 0.f ? v : NEG_SLOPE * v;
            sW[wv][lane] = __expf(v);
        }
        for (int i = g; i < m; i += 8) {
            int s   = sS[wv][i];
            float w = sW[wv][i];
            den += w;
            ushort2 u = *(const ushort2*)(feat2b + (size_t)s * 16 + f2);
            ax += w * bf2f(u.x);
            ay += w * bf2f(u.y);
        }
    }

    ax += __shfl_down(ax, 32); ay += __shfl_down(ay, 32); den += __shfl_down(den, 32);
    ax += __shfl_down(ax, 16); ay += __shfl_down(ay, 16); den += __shfl_down(den, 16);
    ax += __shfl_down(ax, 8);  ay += __shfl_down(ay, 8);  den += __shfl_down(den, 8);

    if (lane < 8) {
        float scale = den > 0.f ? 1.f / den : 0.f;
        size_t o0 = (size_t)nd * 16 + f2;
        float2 o;
        o.x = ax * scale + res[o0];
        o.y = ay * scale + res[o0 + 1];
        *(float2*)(out + o0) = o;
    }
}

// ---------------------------------------------------------------------------
extern "C" void kernel_launch(void* const* d_in, const int* in_sizes, int n_in,
                              void* d_out, int out_size, void* d_ws, size_t ws_size,
                              hipStream_t stream) {
    const float* inputs = (const float*)d_in[0];
    const int*   src    = (const int*)d_in[1];
    const int*   dst    = (const int*)d_in[2];
    const float* W0     = (const float*)d_in[3];
    const float* al0    = (const float*)d_in[4];
    const float* ar0    = (const float*)d_in[5];
    const float* W1     = (const float*)d_in[6];
    const float* al1    = (const float*)d_in[7];
    const float* ar1    = (const float*)d_in[8];
    const float* W2     = (const float*)d_in[9];
    const float* al2    = (const float*)d_in[10];
    const float* ar2    = (const float*)d_in[11];
    const float* resW2  = (const float*)d_in[12];
    float* out = (float*)d_out;

    const size_t NF = (size_t)N_NODES * 128;
    float* ws   = (float*)d_ws;
    float* el   = ws;                                  // N*4
    float* er   = el + (size_t)N_NODES * 4;            // N*4
    float* res2 = er + (size_t)N_NODES * 4;            // N*16
    unsigned short* hbufb  = (unsigned short*)(res2 + (size_t)N_NODES * 16);  // N*128 bf16
    unsigned short* featb  = hbufb + NF;               // N*128 bf16
    unsigned short* feat2b = featb + NF;               // N*16 bf16
    unsigned short* W0p    = feat2b + (size_t)N_NODES * 16;  // 16384
    unsigned short* W1p    = W0p + 16384;                    // 16384
    unsigned short* W2p    = W1p + 16384;                    // 8192
    int* iws = (int*)(W2p + 8192);
    unsigned int* pe = (unsigned int*)iws;             // NBUCK*BCAP padded
    int* sorted_src  = iws + NBUCK * BCAP;             // NBUCK*BCAP padded
    int* deg         = sorted_src + NBUCK * BCAP;      // N
    int* rowptr      = deg + N_NODES;                  // N
    int* bcursor     = rowptr + N_NODES;               // 512

    dim3 blk(256);
    int aggGrid = N_NODES / 4;                         // 25000

    // ---- K1: cursor init + weight pack ----
    init_pack<<<162, blk, 0, stream>>>(bcursor, W0, W1, W2, resW2, W0p, W1p, W2p);
    // ---- K2: partition + layer-0 GEMM ----
    part_gemm0<<<PGRID + GEMMGRID, blk, 0, stream>>>(src, dst, bcursor, pe, N_EDGES,
                                                     inputs, W0p, al0, ar0, featb,
                                                     el, er, N_NODES);
    // ---- K3: finalize CSR ----
    bucket_finalize<<<PGRID, blk, 0, stream>>>(pe, bcursor, rowptr, deg, sorted_src);

    // ---- layer 0 aggregation ----
    gat_agg128<<<aggGrid, blk, 0, stream>>>(rowptr, deg, sorted_src, el, er, featb,
                                            nullptr, hbufb);

    // ---- layer 1 ----
    gemm128_mfma_bf16<<<GEMMGRID, blk, 0, stream>>>(hbufb, W1p, al1, ar1, featb,
                                                    el, er, N_NODES);
    gat_agg128<<<aggGrid, blk, 0, stream>>>(rowptr, deg, sorted_src, el, er, featb,
                                            hbufb, hbufb);

    // ---- layer 2 ----
    gemm16_mfma<<<GEMMGRID, blk, 0, stream>>>(hbufb, W2p, al2, ar2, feat2b, res2,
                                              el, er, N_NODES);
    gat_agg16<<<aggGrid, blk, 0, stream>>>(rowptr, deg, sorted_src, el, er, feat2b,
                                           res2, out);
}

// Round 2
// 375.919 us; speedup vs baseline: 1.0430x; 1.0430x over previous
//
#include <hip/hip_runtime.h>

#define N_NODES 100000
#define N_EDGES 1600000
#define IN_F    128
#define NEG_SLOPE 0.2f
#define NBUCK   512                 // bucket = dst>>8; 391 active
#define BCAP    5120                // padded bucket capacity (mean 4096, +16 sigma)
#define PCHUNK  4096                // edges per partition block
#define PGRID   391                 // ceil(N_EDGES / PCHUNK)
#define GEMMGRID 1563               // ceil(N_NODES / 64)

typedef __attribute__((ext_vector_type(8))) short bf16x8;
typedef __attribute__((ext_vector_type(4))) float f32x4;

__device__ __forceinline__ float bf2f(unsigned short u) {
    return __uint_as_float(((unsigned int)u) << 16);
}

// f32 -> bf16 round-to-nearest-even
__device__ __forceinline__ unsigned short f2bf(float f) {
    unsigned int u = __float_as_uint(f);
    u += 0x7FFFu + ((u >> 16) & 1u);
    return (unsigned short)(u >> 16);
}

// uniform-base + 32-bit-offset load: encourages global_load saddr form
__device__ __forceinline__ unsigned int ld_u32(const char* base, unsigned int off) {
    return *(const unsigned int*)(base + off);
}

// ---------------------------------------------------------------------------
// K1: cursor init (blocks 0..1) + weight pack (blocks 2..161).
// Pack layout: Wp[((nt*4+kt)*64+lane)*8+j] = W[kt*32+(lane>>4)*8+j][nt*16+(lane&15)]
// ---------------------------------------------------------------------------
__global__ __launch_bounds__(256) void init_pack(int* __restrict__ bcursor,
                                                 const float* __restrict__ W0,
                                                 const float* __restrict__ W1,
                                                 const float* __restrict__ W2,
                                                 const float* __restrict__ rW2,
                                                 unsigned short* __restrict__ W0p,
                                                 unsigned short* __restrict__ W1p,
                                                 unsigned short* __restrict__ W2p) {
    const int t = threadIdx.x;
    if (blockIdx.x < 2) {
        int i = blockIdx.x * 256 + t;
        if (i < NBUCK) bcursor[i] = i * BCAP;
        return;
    }
    int gid = (blockIdx.x - 2) * 256 + t;            // < 40960
    const float* W;
    unsigned short* Wp;
    int idx, ncols;
    if (gid < 16384)      { W = W0; Wp = W0p; idx = gid;          ncols = 128; }
    else if (gid < 32768) { W = W1; Wp = W1p; idx = gid - 16384;  ncols = 128; }
    else                  { W = W2; Wp = W2p; idx = gid - 32768;  ncols = 32;  }
    int j  = idx & 7;
    int l  = (idx >> 3) & 63;
    int kt = (idx >> 9) & 3;
    int nt = idx >> 11;
    int k  = kt * 32 + (l >> 4) * 8 + j;
    int n  = nt * 16 + (l & 15);
    float v;
    if (ncols == 128) v = W[k * 128 + n];
    else              v = (n < 16) ? W[k * 16 + n] : rW2[k * 16 + (n - 16)];
    Wp[idx] = f2bf(v);
}

// ---------------------------------------------------------------------------
// K2: edge partition into padded buckets (blocks [0,PGRID)) + layer-0 MFMA
// GEMM (blocks [PGRID, PGRID+GEMMGRID)).
// ---------------------------------------------------------------------------
__global__ __launch_bounds__(256) void part_gemm0(const int* __restrict__ src,
                                                  const int* __restrict__ dst,
                                                  int* __restrict__ bcursor,
                                                  unsigned int* __restrict__ pe, int nE,
                                                  const float* __restrict__ A,
                                                  const unsigned short* __restrict__ Wp,
                                                  const float* __restrict__ al,
                                                  const float* __restrict__ ar,
                                                  unsigned short* __restrict__ featb,
                                                  float* __restrict__ el,
                                                  float* __restrict__ er,
                                                  int nrows) {
    __shared__ int hist[NBUCK];
    __shared__ int lstart[NBUCK];
    __shared__ int gbase[NBUCK];
    __shared__ int curB[NBUCK];
    __shared__ int s[NBUCK];
    __shared__ unsigned int reorder[PCHUNK];

    const int t = threadIdx.x;

    if (blockIdx.x < PGRID) {
        const int start = blockIdx.x * PCHUNK;

        hist[t] = 0; hist[t + 256] = 0;
        __syncthreads();
#pragma unroll
        for (int j = 0; j < PCHUNK / 256; ++j) {
            int e = start + j * 256 + t;
            if (e < nE) atomicAdd(&hist[dst[e] >> 8], 1);
        }
        __syncthreads();
        const int c0 = hist[t];
        const int c1 = hist[t + 256];
        s[t] = c0; s[t + 256] = c1;
        __syncthreads();
        // 512-wide inclusive scan with 256 threads
#pragma unroll
        for (int off = 1; off <= 256; off <<= 1) {
            int x0 = (t >= off) ? s[t - off] : 0;
            int x1 = s[t + 256 - off];
            __syncthreads();
            s[t] += x0; s[t + 256] += x1;
            __syncthreads();
        }
        lstart[t]       = s[t] - c0;
        lstart[t + 256] = s[t + 256] - c1;
        curB[t]         = s[t] - c0;
        curB[t + 256]   = s[t + 256] - c1;
        gbase[t]        = c0 ? atomicAdd(&bcursor[t],       c0) : 0;
        gbase[t + 256]  = c1 ? atomicAdd(&bcursor[t + 256], c1) : 0;
        __syncthreads();

#pragma unroll
        for (int j = 0; j < PCHUNK / 256; ++j) {
            int e = start + j * 256 + t;
            if (e < nE) {
                int d  = dst[e];
                int sv = src[e];
                int b  = d >> 8;
                int pos = atomicAdd(&curB[b], 1);
                reorder[pos] = ((unsigned)sv << 8) | ((unsigned)d & 255u);
            }
        }
        __syncthreads();

        // flush: one thread per bucket writes its contiguous run
        for (int b = t; b < NBUCK; b += 256) {
            int st = lstart[b];
            int en = curB[b];
            int gb = gbase[b];
            for (int k = st; k < en; ++k)
                pe[gb + (k - st)] = reorder[k];
        }
    } else {
        // ---------------- layer-0 GEMM ----------------
        const int bid  = blockIdx.x - PGRID;
        const int wv   = t >> 6;
        const int lane = t & 63;
        const int q    = lane >> 4;
        const int m    = lane & 15;
        const int rb   = bid * 64 + wv * 16;
        const int arow = rb + m;
        const bool rok = arow < nrows;
        const float* Ar = A + (size_t)arow * IN_F;

        f32x4 acc[8];
#pragma unroll
        for (int nt = 0; nt < 8; ++nt) acc[nt] = (f32x4){0.f, 0.f, 0.f, 0.f};

#pragma unroll
        for (int kt = 0; kt < 4; ++kt) {
            bf16x8 afr = (bf16x8){0, 0, 0, 0, 0, 0, 0, 0};
            if (rok) {
                float4 v0 = *(const float4*)(Ar + kt * 32 + q * 8);
                float4 v1 = *(const float4*)(Ar + kt * 32 + q * 8 + 4);
                afr[0] = (short)f2bf(v0.x); afr[1] = (short)f2bf(v0.y);
                afr[2] = (short)f2bf(v0.z); afr[3] = (short)f2bf(v0.w);
                afr[4] = (short)f2bf(v1.x); afr[5] = (short)f2bf(v1.y);
                afr[6] = (short)f2bf(v1.z); afr[7] = (short)f2bf(v1.w);
            }
#pragma unroll
            for (int nt = 0; nt < 8; ++nt) {
                bf16x8 bfr = *(const bf16x8*)(Wp + ((size_t)(nt * 4 + kt) * 64 + lane) * 8);
                acc[nt] = __builtin_amdgcn_mfma_f32_16x16x32_bf16(afr, bfr, acc[nt], 0, 0, 0);
            }
        }

        float pel[16], per[16];
#pragma unroll
        for (int i = 0; i < 16; ++i) { pel[i] = 0.f; per[i] = 0.f; }

#pragma unroll
        for (int nt = 0; nt < 8; ++nt) {
            const int col = nt * 16 + m;
            const float alv = al[col];
            const float arv = ar[col];
            const int h = nt >> 1;
#pragma unroll
            for (int reg = 0; reg < 4; ++reg) {
                int row = rb + q * 4 + reg;
                float a = acc[nt][reg];
                if (row < nrows) featb[(size_t)row * 128 + col] = f2bf(a);
                pel[reg * 4 + h] += a * alv;
                per[reg * 4 + h] += a * arv;
            }
        }
#pragma unroll
        for (int sh = 8; sh > 0; sh >>= 1) {
#pragma unroll
            for (int i = 0; i < 16; ++i) {
                pel[i] += __shfl_down(pel[i], sh);
                per[i] += __shfl_down(per[i], sh);
            }
        }
        if (m == 0) {
#pragma unroll
            for (int reg = 0; reg < 4; ++reg) {
                int row = rb + q * 4 + reg;
                if (row < nrows) {
#pragma unroll
                    for (int h = 0; h < 4; ++h) {
                        el[row * 4 + h] = pel[reg * 4 + h];
                        er[row * 4 + h] = per[reg * 4 + h];
                    }
                }
            }
        }
    }
}

// ---------------------------------------------------------------------------
// K3: per-bucket finalize — degree histogram + local scan -> rowptr/deg,
// within-bucket sort -> sorted_boff (BYTE offsets src*256, = ed & ~255).
// ---------------------------------------------------------------------------
__global__ __launch_bounds__(256) void bucket_finalize(const unsigned int* __restrict__ pe,
                                                       const int* __restrict__ bcursor,
                                                       int* __restrict__ rowptr,
                                                       int* __restrict__ deg,
                                                       int* __restrict__ sorted_boff) {
    __shared__ int deg_l[256];
    __shared__ int s[256];
    __shared__ int cur[256];

    const int b  = blockIdx.x;
    const int t  = threadIdx.x;
    const int base = b * BCAP;
    const int cnt  = bcursor[b] - base;
    const int n    = b * 256 + t;

    deg_l[t] = 0;
    __syncthreads();
    for (int i = t; i < cnt; i += 256)
        atomicAdd(&deg_l[pe[base + i] & 255u], 1);
    __syncthreads();

    const int dv = deg_l[t];
    s[t] = dv;
    __syncthreads();
#pragma unroll
    for (int off = 1; off < 256; off <<= 1) {
        int x = (t >= off) ? s[t - off] : 0;
        __syncthreads();
        s[t] += x;
        __syncthreads();
    }
    const int off_l = s[t] - dv;
    if (n < N_NODES) {
        rowptr[n] = base + off_l;
        deg[n]    = dv;
    }
    cur[t] = off_l;
    __syncthreads();

    for (int i = t; i < cnt; i += 256) {
        unsigned int ed = pe[base + i];
        int pos = atomicAdd(&cur[ed & 255u], 1);
        sorted_boff[base + pos] = (int)(ed & 0xFFFFFF00u);   // src*256 byte offset
    }
}

// ---------------------------------------------------------------------------
// MFMA GEMM, bf16 A (layer 1): featb = Ab @ Wp, el/er fused. Barrier-free.
// ---------------------------------------------------------------------------
__global__ __launch_bounds__(256) void gemm128_mfma_bf16(const unsigned short* __restrict__ Ab,
                                                         const unsigned short* __restrict__ Wp,
                                                         const float* __restrict__ al,
                                                         const float* __restrict__ ar,
                                                         unsigned short* __restrict__ featb,
                                                         float* __restrict__ el,
                                                         float* __restrict__ er,
                                                         int nrows) {
    const int t    = threadIdx.x;
    const int wv   = t >> 6;
    const int lane = t & 63;
    const int q    = lane >> 4;
    const int m    = lane & 15;
    const int rb   = blockIdx.x * 64 + wv * 16;
    const int arow = rb + m;
    const bool rok = arow < nrows;
    const unsigned short* Ar = Ab + (size_t)arow * IN_F;

    f32x4 acc[8];
#pragma unroll
    for (int nt = 0; nt < 8; ++nt) acc[nt] = (f32x4){0.f, 0.f, 0.f, 0.f};

#pragma unroll
    for (int kt = 0; kt < 4; ++kt) {
        bf16x8 afr = (bf16x8){0, 0, 0, 0, 0, 0, 0, 0};
        if (rok) afr = *(const bf16x8*)(Ar + kt * 32 + q * 8);
#pragma unroll
        for (int nt = 0; nt < 8; ++nt) {
            bf16x8 bfr = *(const bf16x8*)(Wp + ((size_t)(nt * 4 + kt) * 64 + lane) * 8);
            acc[nt] = __builtin_amdgcn_mfma_f32_16x16x32_bf16(afr, bfr, acc[nt], 0, 0, 0);
        }
    }

    float pel[16], per[16];
#pragma unroll
    for (int i = 0; i < 16; ++i) { pel[i] = 0.f; per[i] = 0.f; }

#pragma unroll
    for (int nt = 0; nt < 8; ++nt) {
        const int col = nt * 16 + m;
        const float alv = al[col];
        const float arv = ar[col];
        const int h = nt >> 1;
#pragma unroll
        for (int reg = 0; reg < 4; ++reg) {
            int row = rb + q * 4 + reg;
            float a = acc[nt][reg];
            if (row < nrows) featb[(size_t)row * 128 + col] = f2bf(a);
            pel[reg * 4 + h] += a * alv;
            per[reg * 4 + h] += a * arv;
        }
    }
#pragma unroll
    for (int sh = 8; sh > 0; sh >>= 1) {
#pragma unroll
        for (int i = 0; i < 16; ++i) {
            pel[i] += __shfl_down(pel[i], sh);
            per[i] += __shfl_down(per[i], sh);
        }
    }
    if (m == 0) {
#pragma unroll
        for (int reg = 0; reg < 4; ++reg) {
            int row = rb + q * 4 + reg;
            if (row < nrows) {
#pragma unroll
                for (int h = 0; h < 4; ++h) {
                    el[row * 4 + h] = pel[reg * 4 + h];
                    er[row * 4 + h] = per[reg * 4 + h];
                }
            }
        }
    }
}

// ---------------------------------------------------------------------------
// MFMA dual GEMM layer 2 (bf16 A): [feat2b(bf16) | res2(f32)] = A @ [W2|resW2].
// ---------------------------------------------------------------------------
__global__ __launch_bounds__(256) void gemm16_mfma(const unsigned short* __restrict__ Ab,
                                                   const unsigned short* __restrict__ Wp,
                                                   const float* __restrict__ al,
                                                   const float* __restrict__ ar,
                                                   unsigned short* __restrict__ feat2b,
                                                   float* __restrict__ res2,
                                                   float* __restrict__ el,
                                                   float* __restrict__ er,
                                                   int nrows) {
    const int t    = threadIdx.x;
    const int wv   = t >> 6;
    const int lane = t & 63;
    const int q    = lane >> 4;
    const int m    = lane & 15;
    const int rb   = blockIdx.x * 64 + wv * 16;
    const int arow = rb + m;
    const bool rok = arow < nrows;
    const unsigned short* Ar = Ab + (size_t)arow * IN_F;

    f32x4 acc0 = (f32x4){0.f, 0.f, 0.f, 0.f};
    f32x4 acc1 = (f32x4){0.f, 0.f, 0.f, 0.f};

#pragma unroll
    for (int kt = 0; kt < 4; ++kt) {
        bf16x8 afr = (bf16x8){0, 0, 0, 0, 0, 0, 0, 0};
        if (rok) afr = *(const bf16x8*)(Ar + kt * 32 + q * 8);
        bf16x8 b0 = *(const bf16x8*)(Wp + ((size_t)(0 * 4 + kt) * 64 + lane) * 8);
        bf16x8 b1 = *(const bf16x8*)(Wp + ((size_t)(1 * 4 + kt) * 64 + lane) * 8);
        acc0 = __builtin_amdgcn_mfma_f32_16x16x32_bf16(afr, b0, acc0, 0, 0, 0);
        acc1 = __builtin_amdgcn_mfma_f32_16x16x32_bf16(afr, b1, acc1, 0, 0, 0);
    }

    float pel[4], per[4];
    const float alv = al[m];
    const float arv = ar[m];
#pragma unroll
    for (int reg = 0; reg < 4; ++reg) {
        int row = rb + q * 4 + reg;
        float a = acc0[reg];
        if (row < nrows) {
            feat2b[(size_t)row * 16 + m] = f2bf(a);
            res2[(size_t)row * 16 + m]   = acc1[reg];
        }
        pel[reg] = a * alv;
        per[reg] = a * arv;
    }
#pragma unroll
    for (int sh = 8; sh > 0; sh >>= 1) {
#pragma unroll
        for (int reg = 0; reg < 4; ++reg) {
            pel[reg] += __shfl_down(pel[reg], sh);
            per[reg] += __shfl_down(per[reg], sh);
        }
    }
    if (m == 0) {
#pragma unroll
        for (int reg = 0; reg < 4; ++reg) {
            int row = rb + q * 4 + reg;
            if (row < nrows) { el[row] = pel[reg]; er[row] = per[reg]; }
        }
    }
}

// ---------------------------------------------------------------------------
// Pull aggregation, H=4, D=32, bf16 gathers, wave per node, bf16 in/out.
//
// v3: same gather pattern as the 77.7µs baseline (full-row 256B, dword/lane,
// vector addressing) but with per-edge issue cost cut ~40%:
//  - sorted_boff holds src*256 byte offsets -> per-edge address is ONE
//    v_add_u32 on a uniform-base (saddr) load, no 64-bit math, no mul.
//  - offsets read as int4 (ds_read_b128, 1 per 4 edges, broadcast).
//  - weights stored head-major sW[wv][h][68] (68*4B row stride = distinct
//    banks per head group) and read as float4 (ds_read_b128, 1 per 4 edges).
//    LDS ops: 2/edge -> 0.5/edge.
//  - den hoisted out of the inner loop: denv4 += w4 at stage time, one
//    64-lane butterfly reduction at the end.
//  - bf16 unpack via u<<16 / u&0xFFFF0000 (exactly 2 VALU).
//  - no per-edge conditionals: padded lanes carry w=0, offset 0 (row 0).
// ---------------------------------------------------------------------------
__global__ __launch_bounds__(256) void gat_agg128(const int* __restrict__ rowptr,
                                                  const int* __restrict__ deg,
                                                  const int* __restrict__ sorted_boff,
                                                  const float* __restrict__ el,
                                                  const float* __restrict__ er,
                                                  const unsigned short* __restrict__ featb,
                                                  const unsigned short* __restrict__ resb,
                                                  unsigned short* __restrict__ outb) {
    __shared__ __align__(16) int   sS[4][64];
    __shared__ __align__(16) float sW[4][4][68];

    const int wv   = threadIdx.x >> 6;
    const int lane = threadIdx.x & 63;
    const int nd   = blockIdx.x * 4 + wv;

    const int dg = deg[nd];
    const int r0 = rowptr[nd];
    const int h  = lane >> 4;
    const unsigned int lane4 = (unsigned int)(lane << 2);
    const float4 er4 = *(const float4*)(er + nd * 4);
    const char* fb = (const char*)featb;
    const char* eb = (const char*)el;

    float dx = 0.f, dy = 0.f, dz = 0.f, dw = 0.f;
    float ax = 0.f, ay = 0.f;

    for (int base = 0; base < dg; base += 64) {
        int m = dg - base; if (m > 64) m = 64;

        // ---- stage: each lane owns one edge ----
        int boff = 0;
        float4 w4 = {0.f, 0.f, 0.f, 0.f};
        if (lane < m) {
            boff = sorted_boff[r0 + base + lane];
            float4 e4 = *(const float4*)(eb + (unsigned int)(boff >> 4));
            float t_;
            t_ = e4.x + er4.x; t_ = t_ > 0.f ? t_ : NEG_SLOPE * t_; w4.x = __expf(t_);
            t_ = e4.y + er4.y; t_ = t_ > 0.f ? t_ : NEG_SLOPE * t_; w4.y = __expf(t_);
            t_ = e4.z + er4.z; t_ = t_ > 0.f ? t_ : NEG_SLOPE * t_; w4.z = __expf(t_);
            t_ = e4.w + er4.w; t_ = t_ > 0.f ? t_ : NEG_SLOPE * t_; w4.w = __expf(t_);
        }
        // wave-synchronous: same wave writes and reads its slice
        sS[wv][lane]    = boff;
        sW[wv][0][lane] = w4.x;
        sW[wv][1][lane] = w4.y;
        sW[wv][2][lane] = w4.z;
        sW[wv][3][lane] = w4.w;
        dx += w4.x; dy += w4.y; dz += w4.z; dw += w4.w;

        // ---- consume: 8 edges per group, no conditionals ----
        const int mr = (m + 7) & ~7;
        for (int i = 0; i < mr; i += 8) {
            const int4   sa = *(const int4*)(&sS[wv][i]);
            const int4   sb = *(const int4*)(&sS[wv][i + 4]);
            const float4 wa = *(const float4*)(&sW[wv][h][i]);
            const float4 wb = *(const float4*)(&sW[wv][h][i + 4]);

            unsigned int u0 = ld_u32(fb, (unsigned int)sa.x + lane4);
            unsigned int u1 = ld_u32(fb, (unsigned int)sa.y + lane4);
            unsigned int u2 = ld_u32(fb, (unsigned int)sa.z + lane4);
            unsigned int u3 = ld_u32(fb, (unsigned int)sa.w + lane4);
            unsigned int u4 = ld_u32(fb, (unsigned int)sb.x + lane4);
            unsigned int u5 = ld_u32(fb, (unsigned int)sb.y + lane4);
            unsigned int u6 = ld_u32(fb, (unsigned int)sb.z + lane4);
            unsigned int u7 = ld_u32(fb, (unsigned int)sb.w + lane4);

            ax += wa.x * __uint_as_float(u0 << 16);
            ay += wa.x * __uint_as_float(u0 & 0xFFFF0000u);
            ax += wa.y * __uint_as_float(u1 << 16);
            ay += wa.y * __uint_as_float(u1 & 0xFFFF0000u);
            ax += wa.z * __uint_as_float(u2 << 16);
            ay += wa.z * __uint_as_float(u2 & 0xFFFF0000u);
            ax += wa.w * __uint_as_float(u3 << 16);
            ay += wa.w * __uint_as_float(u3 & 0xFFFF0000u);
            ax += wb.x * __uint_as_float(u4 << 16);
            ay += wb.x * __uint_as_float(u4 & 0xFFFF0000u);
            ax += wb.y * __uint_as_float(u5 << 16);
            ay += wb.y * __uint_as_float(u5 & 0xFFFF0000u);
            ax += wb.z * __uint_as_float(u6 << 16);
            ay += wb.z * __uint_as_float(u6 & 0xFFFF0000u);
            ax += wb.w * __uint_as_float(u7 << 16);
            ay += wb.w * __uint_as_float(u7 & 0xFFFF0000u);
        }
    }

    // den: butterfly-reduce the staged weight sums across all 64 lanes
#pragma unroll
    for (int sh = 1; sh < 64; sh <<= 1) {
        dx += __shfl_xor(dx, sh);
        dy += __shfl_xor(dy, sh);
        dz += __shfl_xor(dz, sh);
        dw += __shfl_xor(dw, sh);
    }
    float den = (h == 0) ? dx : (h == 1) ? dy : (h == 2) ? dz : dw;

    float scale = den > 0.f ? 1.f / den : 0.f;
    float ox = ax * scale, oy = ay * scale;
    size_t o0 = (size_t)nd * 128 + lane * 2;
    if (resb) {
        ushort2 rv = *(const ushort2*)(resb + o0);
        ox += bf2f(rv.x);
        oy += bf2f(rv.y);
    }
    ox = fmaxf(ox, 0.f);
    oy = fmaxf(oy, 0.f);
    ushort2 ou;
    ou.x = f2bf(ox);
    ou.y = f2bf(oy);
    *(ushort2*)(outb + o0) = ou;
}

// ---------------------------------------------------------------------------
// Pull aggregation, H=1, C=16: wave per node, LDS staging, 8 edge-groups of
// 8 lanes; lane owns a feature pair. Final output f32 (+res2).
// sorted_boff holds src*256; feat2b byte = boff>>3, el byte = boff>>6.
// ---------------------------------------------------------------------------
__global__ __launch_bounds__(256) void gat_agg16(const int* __restrict__ rowptr,
                                                 const int* __restrict__ deg,
                                                 const int* __restrict__ sorted_boff,
                                                 const float* __restrict__ el,
                                                 const float* __restrict__ er,
                                                 const unsigned short* __restrict__ feat2b,
                                                 const float* __restrict__ res,
                                                 float* __restrict__ out) {
    __shared__ int   sS[4][64];
    __shared__ float sW[4][64];

    const int wv   = threadIdx.x >> 6;
    const int lane = threadIdx.x & 63;
    const int nd   = blockIdx.x * 4 + (threadIdx.x >> 6);
    const int g    = lane >> 3;
    const unsigned int flane4 = (unsigned int)((lane & 7) << 2);
    const char* f2base = (const char*)feat2b;
    const char* eb = (const char*)el;

    const int dg = deg[nd];
    const int r0 = rowptr[nd];
    const float erd = er[nd];

    float ax = 0.f, ay = 0.f, den = 0.f;

    for (int base = 0; base < dg; base += 64) {
        int m = dg - base; if (m > 64) m = 64;
        if (lane < m) {
            int boff = sorted_boff[r0 + base + lane];
            sS[wv][lane] = boff;
            float v = *(const float*)(eb + (unsigned int)(boff >> 6)) + erd;
            v = v > 0.f ? v : NEG_SLOPE * v;
            sW[wv][lane] = __expf(v);
        }
        for (int i = g; i < m; i += 8) {
            int bo  = sS[wv][i];
            float w = sW[wv][i];
            den += w;
            unsigned int u = *(const unsigned int*)(f2base + (unsigned int)(bo >> 3) + flane4);
            ax += w * __uint_as_float(u << 16);
            ay += w * __uint_as_float(u & 0xFFFF0000u);
        }
    }

    ax += __shfl_down(ax, 32); ay += __shfl_down(ay, 32); den += __shfl_down(den, 32);
    ax += __shfl_down(ax, 16); ay += __shfl_down(ay, 16); den += __shfl_down(den, 16);
    ax += __shfl_down(ax, 8);  ay += __shfl_down(ay, 8);  den += __shfl_down(den, 8);

    if (lane < 8) {
        float scale = den > 0.f ? 1.f / den : 0.f;
        size_t o0 = (size_t)nd * 16 + ((lane & 7) << 1);
        float2 o;
        o.x = ax * scale + res[o0];
        o.y = ay * scale + res[o0 + 1];
        *(float2*)(out + o0) = o;
    }
}

// ---------------------------------------------------------------------------
extern "C" void kernel_launch(void* const* d_in, const int* in_sizes, int n_in,
                              void* d_out, int out_size, void* d_ws, size_t ws_size,
                              hipStream_t stream) {
    const float* inputs = (const float*)d_in[0];
    const int*   src    = (const int*)d_in[1];
    const int*   dst    = (const int*)d_in[2];
    const float* W0     = (const float*)d_in[3];
    const float* al0    = (const float*)d_in[4];
    const float* ar0    = (const float*)d_in[5];
    const float* W1     = (const float*)d_in[6];
    const float* al1    = (const float*)d_in[7];
    const float* ar1    = (const float*)d_in[8];
    const float* W2     = (const float*)d_in[9];
    const float* al2    = (const float*)d_in[10];
    const float* ar2    = (const float*)d_in[11];
    const float* resW2  = (const float*)d_in[12];
    float* out = (float*)d_out;

    const size_t NF = (size_t)N_NODES * 128;
    float* ws   = (float*)d_ws;
    float* el   = ws;                                  // N*4
    float* er   = el + (size_t)N_NODES * 4;            // N*4
    float* res2 = er + (size_t)N_NODES * 4;            // N*16
    unsigned short* hbufb  = (unsigned short*)(res2 + (size_t)N_NODES * 16);  // N*128 bf16
    unsigned short* featb  = hbufb + NF;               // N*128 bf16
    unsigned short* feat2b = featb + NF;               // N*16 bf16
    unsigned short* W0p    = feat2b + (size_t)N_NODES * 16;  // 16384
    unsigned short* W1p    = W0p + 16384;                    // 16384
    unsigned short* W2p    = W1p + 16384;                    // 8192
    int* iws = (int*)(W2p + 8192);
    unsigned int* pe = (unsigned int*)iws;             // NBUCK*BCAP padded
    int* sorted_boff = iws + NBUCK * BCAP;             // NBUCK*BCAP padded
    int* deg         = sorted_boff + NBUCK * BCAP;     // N
    int* rowptr      = deg + N_NODES;                  // N
    int* bcursor     = rowptr + N_NODES;               // 512

    dim3 blk(256);
    int aggGrid = N_NODES / 4;                         // 25000

    // ---- K1: cursor init + weight pack ----
    init_pack<<<162, blk, 0, stream>>>(bcursor, W0, W1, W2, resW2, W0p, W1p, W2p);
    // ---- K2: partition + layer-0 GEMM ----
    part_gemm0<<<PGRID + GEMMGRID, blk, 0, stream>>>(src, dst, bcursor, pe, N_EDGES,
                                                     inputs, W0p, al0, ar0, featb,
                                                     el, er, N_NODES);
    // ---- K3: finalize CSR ----
    bucket_finalize<<<PGRID, blk, 0, stream>>>(pe, bcursor, rowptr, deg, sorted_boff);

    // ---- layer 0 aggregation ----
    gat_agg128<<<aggGrid, blk, 0, stream>>>(rowptr, deg, sorted_boff, el, er, featb,
                                            nullptr, hbufb);

    // ---- layer 1 ----
    gemm128_mfma_bf16<<<GEMMGRID, blk, 0, stream>>>(hbufb, W1p, al1, ar1, featb,
                                                    el, er, N_NODES);
    gat_agg128<<<aggGrid, blk, 0, stream>>>(rowptr, deg, sorted_boff, el, er, featb,
                                            hbufb, hbufb);

    // ---- layer 2 ----
    gemm16_mfma<<<GEMMGRID, blk, 0, stream>>>(hbufb, W2p, al2, ar2, feat2b, res2,
                                              el, er, N_NODES);
    gat_agg16<<<aggGrid, blk, 0, stream>>>(rowptr, deg, sorted_boff, el, er, feat2b,
                                           res2, out);
}